// Round 6
// baseline (81.127 us; speedup 1.0000x reference)
//
#include <hip/hip_runtime.h>
#include <math.h>

#define BB 64
#define HH 512
#define WW 512
#define HWQ (HH*WW)
#define NTOT ((size_t)BB*HWQ)
#define PR 15

// ws layout:
//   [0, NTOT) bytes : vertical box sums as uint8 (exact ints 0..31)
//   [NTOT, ...)     : doubles: [0..63] combined-bce slots,
//                     [64+8b+{0,1,2}] = TP_b, sumP_b, sumT_b (64B-padded per image)
#define ACC_DOUBLES (64 + 8*BB)

// vertical 31-tap box sum of binary target -> uint8 (+ acc zeroing in block 0)
// 16-row segments, 1024 blocks (4/CU), 2-accumulator init for ILP.
__global__ __launch_bounds__(256) void k_vsum(const float* __restrict__ tgt,
                                              unsigned char* __restrict__ vs,
                                              double* __restrict__ acc) {
  if (blockIdx.x == 0) {
    for (int i = threadIdx.x; i < ACC_DOUBLES; i += 256) acc[i] = 0.0;
  }
  int gid = blockIdx.x * 256 + threadIdx.x;     // 262144 threads
  int x   = (gid & 127) * 4;                    // 128 float4 column groups
  int seg = (gid >> 7) & 31;                    // 32 row segments of 16
  int b   = gid >> 12;
  const float* timg = tgt + (size_t)b * HWQ;
  unsigned char* vimg = vs + (size_t)b * HWQ;
  int y0 = seg * 16;
  int lo = y0 - PR; if (lo < 0) lo = 0;
  int hi = y0 + PR;                             // y0+15 <= 511 always
  float4 s  = make_float4(0.f, 0.f, 0.f, 0.f);
  float4 s2 = make_float4(0.f, 0.f, 0.f, 0.f);
  int r = lo;
  for (; r + 1 <= hi; r += 2) {
    const float4 ta = *(const float4*)(timg + (size_t)r * WW + x);
    const float4 tb = *(const float4*)(timg + (size_t)(r + 1) * WW + x);
    s.x  += ta.x; s.y  += ta.y; s.z  += ta.z; s.w  += ta.w;
    s2.x += tb.x; s2.y += tb.y; s2.z += tb.z; s2.w += tb.w;
  }
  if (r <= hi) {
    const float4 ta = *(const float4*)(timg + (size_t)r * WW + x);
    s.x += ta.x; s.y += ta.y; s.z += ta.z; s.w += ta.w;
  }
  s.x += s2.x; s.y += s2.y; s.z += s2.z; s.w += s2.w;
#pragma unroll 4
  for (int y = y0; y < y0 + 16; ++y) {
    uchar4 o;
    o.x = (unsigned char)(s.x + 0.5f);
    o.y = (unsigned char)(s.y + 0.5f);
    o.z = (unsigned char)(s.z + 0.5f);
    o.w = (unsigned char)(s.w + 0.5f);
    *(uchar4*)(vimg + (size_t)y * WW + x) = o;
    int ra = y + PR + 1, rs = y - PR;
    if (ra < HH) {
      const float4 t = *(const float4*)(timg + (size_t)ra * WW + x);
      s.x += t.x; s.y += t.y; s.z += t.z; s.w += t.w;
    }
    if (rs >= 0) {
      const float4 t = *(const float4*)(timg + (size_t)rs * WW + x);
      s.x -= t.x; s.y -= t.y; s.z -= t.z; s.w -= t.w;
    }
  }
}

__device__ inline float wredf(float v) {
#pragma unroll
  for (int o = 32; o > 0; o >>= 1) v += __shfl_down(v, o, 64);
  return v;
}

// 8-byte-granular masked load (col boundaries 0/512 are 8B-aligned)
__device__ inline uint2 ld8(const unsigned char* __restrict__ row, int off, bool ok) {
  int oc = ok ? off : 0;
  uint2 v = *(const uint2*)(row + oc);
  if (!ok) { v.x = 0u; v.y = 0u; }
  return v;
}

__device__ inline int sum4b(unsigned x) {  // sum of the 4 bytes
  unsigned t = (x & 0x00FF00FFu) + ((x >> 8) & 0x00FF00FFu);
  return (int)((t + (t >> 16)) & 0xFFFFu);
}

// window byte I (0..47) <-> vs col x0-16+I ; compile-time I -> folds to one bfe
#define VSWORD(I) ((I) < 8  ? (((I)&7) < 4 ? w0.x : w0.y) : \
                   (I) < 16 ? (((I)&7) < 4 ? w1.x : w1.y) : \
                   (I) < 24 ? (((I)&7) < 4 ? w2.x : w2.y) : \
                   (I) < 32 ? (((I)&7) < 4 ? w3.x : w3.y) : \
                   (I) < 40 ? (((I)&7) < 4 ? w4.x : w4.y) : \
                              (((I)&7) < 4 ? w5.x : w5.y))
#define BGET(I) ((int)((VSWORD(I) >> (((I)&3)*8)) & 0xffu))

// one output column: M*/Z*/Q* = rows y-1,y,y+1 at cols c-1,c,c+1 ; PV = pred[c]
#define STEP(C, MA,MB,MC, ZA,ZB,ZC, QA,QB,QC, PV) do {            \
    float gxv = (MC - MA) + 2.f*(ZC - ZA) + (QC - QA);            \
    float gyv = (QA - MA) + 2.f*(QB - MB) + (QC - MC);            \
    float tb  = sqrtf(gxv*gxv + gyv*gyv + 1e-12f);                \
    float tcv = ZB; float pvv = PV;                               \
    float qq  = (tcv > 0.5f) ? pvv : 1.f - pvv;                   \
    float lg  = __log2f(qq);                                      \
    float pooled = (float)sw * (1.f/961.f);                       \
    float wgt = 0.8f + 5.f*tb + 1.5f*fabsf(pooled - tcv);         \
    a_c += wgt*lg; a_pt += pvv*tcv; a_p += pvv; a_t += tcv;       \
    sw += BGET((C)+32) - BGET((C)+1);                             \
  } while (0)

// main fused kernel: block = 8 rows of one image; wave = 2 rows x 32 lanes;
// lane -> 16 cols. All state in NAMED scalars/vectors.
__global__ __launch_bounds__(256) void k_main(const float* __restrict__ pred,
                                              const float* __restrict__ tgt,
                                              const unsigned char* __restrict__ vs,
                                              double* __restrict__ acc) {
  __shared__ float s_red[4][4];

  int blk = blockIdx.x;            // 64*64
  int b   = blk >> 6;
  int y0  = (blk & 63) * 8;
  int tid = threadIdx.x;
  int wv = tid >> 6, lane = tid & 63;
  int lh = lane >> 5;              // row half within wave
  int li = lane & 31;              // position within row
  int y  = y0 + wv * 2 + lh;
  int x0 = li * 16;

  const float* pimg = pred + (size_t)b * HWQ;
  const float* timg = tgt  + (size_t)b * HWQ;
  const unsigned char* vimg = vs + (size_t)b * HWQ;

  // pred: own 16 cols
  const float* prow = pimg + (size_t)y * WW + x0;
  float4 p0 = *(const float4*)prow;
  float4 p1 = *(const float4*)(prow + 4);
  float4 p2 = *(const float4*)(prow + 8);
  float4 p3 = *(const float4*)(prow + 12);

  // target rows y-1,y,y+1, own 16 cols (row addr clamped; OOB row zeroed)
  const float* trm = timg + (size_t)(y > 0 ? y - 1 : 0) * WW + x0;
  const float* tr0 = timg + (size_t)y * WW + x0;
  const float* trp = timg + (size_t)(y < HH - 1 ? y + 1 : HH - 1) * WW + x0;
  float4 m0 = *(const float4*)trm, m1 = *(const float4*)(trm + 4);
  float4 m2 = *(const float4*)(trm + 8), m3 = *(const float4*)(trm + 12);
  float4 z0 = *(const float4*)tr0, z1 = *(const float4*)(tr0 + 4);
  float4 z2 = *(const float4*)(tr0 + 8), z3 = *(const float4*)(tr0 + 12);
  float4 q0 = *(const float4*)trp, q1 = *(const float4*)(trp + 4);
  float4 q2 = *(const float4*)(trp + 8), q3 = *(const float4*)(trp + 12);
  if (y == 0) {
    m0 = make_float4(0,0,0,0); m1 = make_float4(0,0,0,0);
    m2 = make_float4(0,0,0,0); m3 = make_float4(0,0,0,0);
  }
  if (y == HH - 1) {
    q0 = make_float4(0,0,0,0); q1 = make_float4(0,0,0,0);
    q2 = make_float4(0,0,0,0); q3 = make_float4(0,0,0,0);
  }

  // vs window bytes: cols x0-16 .. x0+31 as 6 uint2 (masked at row ends)
  const unsigned char* vrow = vimg + (size_t)y * WW;
  bool okL = (li != 0), okR = (li != 31);
  uint2 w0 = ld8(vrow, x0 - 16, okL);
  uint2 w1 = ld8(vrow, x0 - 8,  okL);
  uint2 w2 = *(const uint2*)(vrow + x0);
  uint2 w3 = *(const uint2*)(vrow + x0 + 8);
  uint2 w4 = ld8(vrow, x0 + 16, okR);
  uint2 w5 = ld8(vrow, x0 + 24, okR);

  // horizontal halo via shuffles (masked at row-half boundaries)
  float m_l = __shfl_up(m3.w, 1, 64);  float m_r = __shfl_down(m0.x, 1, 64);
  float z_l = __shfl_up(z3.w, 1, 64);  float z_r = __shfl_down(z0.x, 1, 64);
  float q_l = __shfl_up(q3.w, 1, 64);  float q_r = __shfl_down(q0.x, 1, 64);
  m_l = okL ? m_l : 0.f;  z_l = okL ? z_l : 0.f;  q_l = okL ? q_l : 0.f;
  m_r = okR ? m_r : 0.f;  z_r = okR ? z_r : 0.f;  q_r = okR ? q_r : 0.f;

  // initial 31-window sum for col x0 (bytes 1..31) via packed byte adds:
  // 8 words, byte-lane sums <= 8*31 = 248 < 256 -> no carry
  unsigned psum = w0.x + w0.y + w1.x + w1.y + w2.x + w2.y + w3.x + w3.y;
  int sw = sum4b(psum) - (int)(w0.x & 0xffu);

  float a_c = 0.f, a_pt = 0.f, a_p = 0.f, a_t = 0.f;
  STEP(0,  m_l,  m0.x, m0.y,  z_l,  z0.x, z0.y,  q_l,  q0.x, q0.y,  p0.x);
  STEP(1,  m0.x, m0.y, m0.z,  z0.x, z0.y, z0.z,  q0.x, q0.y, q0.z,  p0.y);
  STEP(2,  m0.y, m0.z, m0.w,  z0.y, z0.z, z0.w,  q0.y, q0.z, q0.w,  p0.z);
  STEP(3,  m0.z, m0.w, m1.x,  z0.z, z0.w, z1.x,  q0.z, q0.w, q1.x,  p0.w);
  STEP(4,  m0.w, m1.x, m1.y,  z0.w, z1.x, z1.y,  q0.w, q1.x, q1.y,  p1.x);
  STEP(5,  m1.x, m1.y, m1.z,  z1.x, z1.y, z1.z,  q1.x, q1.y, q1.z,  p1.y);
  STEP(6,  m1.y, m1.z, m1.w,  z1.y, z1.z, z1.w,  q1.y, q1.z, q1.w,  p1.z);
  STEP(7,  m1.z, m1.w, m2.x,  z1.z, z1.w, z2.x,  q1.z, q1.w, q2.x,  p1.w);
  STEP(8,  m1.w, m2.x, m2.y,  z1.w, z2.x, z2.y,  q1.w, q2.x, q2.y,  p2.x);
  STEP(9,  m2.x, m2.y, m2.z,  z2.x, z2.y, z2.z,  q2.x, q2.y, q2.z,  p2.y);
  STEP(10, m2.y, m2.z, m2.w,  z2.y, z2.z, z2.w,  q2.y, q2.z, q2.w,  p2.z);
  STEP(11, m2.z, m2.w, m3.x,  z2.z, z2.w, z3.x,  q2.z, q2.w, q3.x,  p2.w);
  STEP(12, m2.w, m3.x, m3.y,  z2.w, z3.x, z3.y,  q2.w, q3.x, q3.y,  p3.x);
  STEP(13, m3.x, m3.y, m3.z,  z3.x, z3.y, z3.z,  q3.x, q3.y, q3.z,  p3.y);
  STEP(14, m3.y, m3.z, m3.w,  z3.y, z3.z, z3.w,  q3.y, q3.z, q3.w,  p3.z);
  STEP(15, m3.z, m3.w, m_r,   z3.z, z3.w, z_r,   q3.z, q3.w, q_r,   p3.w);

  a_c = wredf(a_c); a_pt = wredf(a_pt); a_p = wredf(a_p); a_t = wredf(a_t);
  if (lane == 0) {
    s_red[wv][0] = a_c; s_red[wv][1] = a_pt; s_red[wv][2] = a_p; s_red[wv][3] = a_t;
  }
  __syncthreads();
  if (tid == 0) {
    float rc = 0, rpt = 0, rp = 0, rt = 0;
    for (int w2i = 0; w2i < 4; ++w2i) {
      rc += s_red[w2i][0]; rpt += s_red[w2i][1]; rp += s_red[w2i][2]; rt += s_red[w2i][3];
    }
    atomicAdd(&acc[blk & 63],       (double)rc);
    atomicAdd(&acc[64 + 8*b + 0],   (double)rpt);
    atomicAdd(&acc[64 + 8*b + 1],   (double)rp);
    atomicAdd(&acc[64 + 8*b + 2],   (double)rt);
  }
}

__global__ void k_final(const double* __restrict__ acc, float* __restrict__ out) {
  int t = threadIdx.x;  // 64 threads = 1 wave
  double cs = acc[t];
  double TP = acc[64 + 8*t], Ps = acc[64 + 8*t + 1], Ts = acc[64 + 8*t + 2];
  double FP = Ps - TP, FN = Ts - TP;
  double tv = (TP + 1e-6) / (TP + 0.3 * FP + 0.7 * FN + 1e-6);
  double om = 1.0 - tv;
  if (om < 0.0) om = 0.0;
  double term = pow(om, 1.0 / 1.33);
#pragma unroll
  for (int o = 32; o > 0; o >>= 1) {
    cs   += __shfl_down(cs, o, 64);
    term += __shfl_down(term, o, 64);
  }
  if (t == 0) {
    double ftl = term / 64.0;
    double n = (double)NTOT;
    // combined weighted-BCE sum: bce = -ln2 * log2(q)
    out[0] = (float)(ftl - 0.6931471805599453 * cs / n);
  }
}

extern "C" void kernel_launch(void* const* d_in, const int* in_sizes, int n_in,
                              void* d_out, int out_size, void* d_ws, size_t ws_size,
                              hipStream_t stream) {
  (void)in_sizes; (void)n_in; (void)out_size; (void)ws_size;
  const float* pred = (const float*)d_in[0];
  const float* tgt  = (const float*)d_in[1];
  unsigned char* vsb = (unsigned char*)d_ws;
  double* acc = (double*)((char*)d_ws + NTOT);

  k_vsum<<<1024, 256, 0, stream>>>(tgt, vsb, acc);
  k_main<<<BB * 64, 256, 0, stream>>>(pred, tgt, vsb, acc);
  k_final<<<1, 64, 0, stream>>>(acc, (float*)d_out);
}

// Round 7
// 76.156 us; speedup vs baseline: 1.0653x; 1.0653x over previous
//
#include <hip/hip_runtime.h>
#include <math.h>

#define BB 64
#define HH 512
#define WW 512
#define HWQ (HH*WW)
#define NTOT ((size_t)BB*HWQ)
#define PR 15

// ws layout:
//  [0, NTOT) bytes : vt8 per px = vsum(0..31) | t<<5 | t(y-1)<<6 | t(y+1)<<7
//  then doubles:
//   [0..63]      a_c slots (k_main atomics; zeroed by k_vsum block 0)
//   [64+8b+0,1]  TP_b, sumP_b (k_main atomics; zeroed by k_vsum block 0)
//   [576+blk]    k_vsum per-block t-count partials (plain stores, no zero needed)
#define ACC_MAIN_DOUBLES 576
#define VS_BLOCKS 2048

__device__ inline float wredf(float v) {
#pragma unroll
  for (int o = 32; o > 0; o >>= 1) v += __shfl_down(v, o, 64);
  return v;
}

// vertical 31-tap box sum + 3-row t-bit context, fused into one byte/px.
// 2 cols/thread, 16-row segments -> 2048 blocks (full CU residency).
__global__ __launch_bounds__(256) void k_vsum(const float* __restrict__ tgt,
                                              unsigned char* __restrict__ vt,
                                              double* __restrict__ accz,
                                              double* __restrict__ tpart) {
  if (blockIdx.x == 0) {
    for (int i = threadIdx.x; i < ACC_MAIN_DOUBLES; i += 256) accz[i] = 0.0;
  }
  int gid = blockIdx.x * 256 + threadIdx.x;   // 524288 threads
  int x   = (gid & 255) * 2;                  // 256 col-pairs
  int seg = (gid >> 8) & 31;                  // 32 segments of 16 rows
  int b   = gid >> 13;
  const float* timg = tgt + (size_t)b * HWQ;
  unsigned char* vimg = vt + (size_t)b * HWQ;
  int y0 = seg * 16;
  int lo = y0 - PR; if (lo < 0) lo = 0;
  float sx = 0.f, sy = 0.f;
  unsigned srA = 0u, srB = 0u;                // t-bit shift registers (newest = bit0)
  for (int r = lo; r <= y0 + PR; ++r) {
    const float2 t = *(const float2*)(timg + (size_t)r * WW + x);
    sx += t.x; sy += t.y;
    srA = (srA << 1) | (unsigned)t.x;         // t is exactly 0.0f / 1.0f
    srB = (srB << 1) | (unsigned)t.y;
  }
  int tcnt = 0;
  for (int y = y0; y < y0 + 16; ++y) {
    // at store time: bit15 = t(y), bit16 = t(y-1), bit14 = t(y+1); OOB rows = 0
    unsigned ca = (unsigned)(sx + 0.5f);
    unsigned cb = (unsigned)(sy + 0.5f);
    unsigned ba = ca | ((srA >> 10) & 0x20u) | (((srA >> 16) & 1u) << 6) | (((srA >> 14) & 1u) << 7);
    unsigned bb = cb | ((srB >> 10) & 0x20u) | (((srB >> 16) & 1u) << 6) | (((srB >> 14) & 1u) << 7);
    *(unsigned short*)(vimg + (size_t)y * WW + x) = (unsigned short)(ba | (bb << 8));
    tcnt += (int)((srA >> 15) & 1u) + (int)((srB >> 15) & 1u);
    int ra = y + PR + 1, rs = y - PR;
    if (ra < HH) {
      const float2 t = *(const float2*)(timg + (size_t)ra * WW + x);
      sx += t.x; sy += t.y;
      srA = (srA << 1) | (unsigned)t.x;
      srB = (srB << 1) | (unsigned)t.y;
    } else { srA <<= 1; srB <<= 1; }          // keep shifting zeros past the bottom edge
    if (rs >= 0) {
      const float2 t = *(const float2*)(timg + (size_t)rs * WW + x);
      sx -= t.x; sy -= t.y;
    }
  }
  float tf = wredf((float)tcnt);              // exact: block sum <= 8192
  __shared__ float s_t[4];
  int wv = threadIdx.x >> 6, lane = threadIdx.x & 63;
  if (lane == 0) s_t[wv] = tf;
  __syncthreads();
  if (threadIdx.x == 0)
    tpart[blockIdx.x] = (double)(s_t[0] + s_t[1] + s_t[2] + s_t[3]);
}

// 8-byte-granular masked load (col boundaries are 8B-aligned)
__device__ inline uint2 ld8(const unsigned char* __restrict__ row, int off) {
  bool ok = (off >= 0) & (off <= WW - 8);
  int oc = ok ? off : 0;
  uint2 v = *(const uint2*)(row + oc);
  if (!ok) { v.x = 0u; v.y = 0u; }
  return v;
}

__device__ inline int sum4b(unsigned x) {     // sum of the 4 bytes
  unsigned t = (x & 0x00FF00FFu) + ((x >> 8) & 0x00FF00FFu);
  return (int)((t + (t >> 16)) & 0xFFFFu);
}

// window byte I (0..39) <-> col x0-16+I ; I compile-time -> folds to one bfe
#define VTW(I) ((I) < 8  ? (((I)&7) < 4 ? w0.x : w0.y) : \
                (I) < 16 ? (((I)&7) < 4 ? w1.x : w1.y) : \
                (I) < 24 ? (((I)&7) < 4 ? w2.x : w2.y) : \
                (I) < 32 ? (((I)&7) < 4 ? w3.x : w3.y) : \
                           (((I)&7) < 4 ? w4.x : w4.y))
#define BGET5(I) ((int)((VTW(I) >> (((I)&3)*8)) & 31u))   // 5-bit vsum field

#define UB(W,J) ((int)(((W) >> (8*(J))) & 7u))            // u byte (0..4)
#define VB(W,J) ((int)(((W) >> (8*(J))) & 3u))            // v+1 byte (0..2)

// one output column
#define STEP(C, UM, UP, VM, VC, VP, TCI, PV) do {                     \
    int gx = (UP) - (UM);                                             \
    int gy = (VM) + 2*(VC) + (VP) - 4;                                \
    float tb = __builtin_amdgcn_sqrtf((float)(gx*gx + gy*gy) + 1e-12f); \
    float qq = (TCI) ? (PV) : 1.f - (PV);                             \
    float lg = __log2f(qq);                                           \
    int   di = (TCI) ? (961 - sw) : sw;                               \
    float wgt = fmaf(5.f, tb, fmaf(1.5608741e-3f, (float)di, 0.8f));  \
    a_c = fmaf(wgt, lg, a_c);                                         \
    a_pt += (TCI) ? (PV) : 0.f;                                       \
    a_p  += (PV);                                                     \
    sw += BGET5((C)+32) - BGET5((C)+1);                               \
  } while (0)

// main fused kernel: reads ONLY pred f32 + one vt8 row window per output row.
__global__ __launch_bounds__(256) void k_main(const float* __restrict__ pred,
                                              const unsigned char* __restrict__ vt,
                                              double* __restrict__ acc) {
  __shared__ float s_red[4][3];
  int blk = blockIdx.x;            // BB*128
  int b   = blk >> 7;
  int y0  = (blk & 127) * 4;
  int tid = threadIdx.x;
  int wv = tid >> 6, lane = tid & 63;
  int y  = y0 + wv;
  int x0 = lane * 8;

  const float* prow = pred + (size_t)b * HWQ + (size_t)y * WW + x0;
  float4 pA = *(const float4*)prow;
  float4 pB = *(const float4*)(prow + 4);

  const unsigned char* vrow = vt + (size_t)b * HWQ + (size_t)y * WW;
  uint2 w0 = ld8(vrow, x0 - 16);
  uint2 w1 = ld8(vrow, x0 - 8);
  uint2 w2 = *(const uint2*)(vrow + x0);      // always in-bounds
  uint2 w3 = ld8(vrow, x0 + 8);
  uint2 w4 = ld8(vrow, x0 + 16);

  // packed-byte vertical sobel composites from embedded m/z/q bits
  unsigned zl = (w2.x >> 5) & 0x01010101u, zh = (w2.y >> 5) & 0x01010101u;
  unsigned ml = (w2.x >> 6) & 0x01010101u, mh = (w2.y >> 6) & 0x01010101u;
  unsigned ql = (w2.x >> 7) & 0x01010101u, qh = (w2.y >> 7) & 0x01010101u;
  unsigned uLo = ml + ql + 2u * zl;           // u = m+2z+q, bytes 0..4
  unsigned uHi = mh + qh + 2u * zh;
  unsigned vLo = (ql + 0x01010101u) - ml;     // v+1, bytes 0..2 (no borrow)
  unsigned vHi = (qh + 0x01010101u) - mh;
  // halos: col x0-1 = byte7 of w1 (0-masked at edge), col x0+8 = byte0 of w3
  int zm1 = (int)((w1.y >> 29) & 1u), mm1 = (int)((w1.y >> 30) & 1u), qm1 = (int)(w1.y >> 31);
  int zp8 = (int)((w3.x >> 5) & 1u),  mp8 = (int)((w3.x >> 6) & 1u),  qp8 = (int)((w3.x >> 7) & 1u);
  int uM1 = mm1 + 2*zm1 + qm1, vM1 = qm1 - mm1 + 1;
  int uP8 = mp8 + 2*zp8 + qp8, vP8 = qp8 - mp8 + 1;

  int u0=UB(uLo,0), u1=UB(uLo,1), u2c=UB(uLo,2), u3=UB(uLo,3);
  int u4=UB(uHi,0), u5=UB(uHi,1), u6=UB(uHi,2), u7=UB(uHi,3);
  int v0=VB(vLo,0), v1=VB(vLo,1), v2c=VB(vLo,2), v3=VB(vLo,3);
  int v4=VB(vHi,0), v5=VB(vHi,1), v6=VB(vHi,2), v7=VB(vHi,3);
  int t0=(int)((w2.x>>5)&1u),  t1=(int)((w2.x>>13)&1u), t2=(int)((w2.x>>21)&1u), t3=(int)((w2.x>>29)&1u);
  int t4=(int)((w2.y>>5)&1u),  t5=(int)((w2.y>>13)&1u), t6=(int)((w2.y>>21)&1u), t7=(int)((w2.y>>29)&1u);

  // initial 31-window vsum for col x0: bytes 1..31 (5-bit fields, packed adds, max 248)
  unsigned p0 = (w0.x & 0x1F1F1F1Fu) + (w0.y & 0x1F1F1F1Fu)
              + (w1.x & 0x1F1F1F1Fu) + (w1.y & 0x1F1F1F1Fu)
              + (w2.x & 0x1F1F1F1Fu) + (w2.y & 0x1F1F1F1Fu)
              + (w3.x & 0x1F1F1F1Fu) + (w3.y & 0x1F1F1F1Fu);
  int sw = sum4b(p0) - (int)(w0.x & 0x1Fu);

  float a_c = 0.f, a_pt = 0.f, a_p = 0.f;
  STEP(0, uM1, u1,  vM1, v0,  v1,  t0, pA.x);
  STEP(1, u0,  u2c, v0,  v1,  v2c, t1, pA.y);
  STEP(2, u1,  u3,  v1,  v2c, v3,  t2, pA.z);
  STEP(3, u2c, u4,  v2c, v3,  v4,  t3, pA.w);
  STEP(4, u3,  u5,  v3,  v4,  v5,  t4, pB.x);
  STEP(5, u4,  u6,  v4,  v5,  v6,  t5, pB.y);
  STEP(6, u5,  u7,  v5,  v6,  v7,  t6, pB.z);
  STEP(7, u6,  uP8, v6,  v7,  vP8, t7, pB.w);

  a_c = wredf(a_c); a_pt = wredf(a_pt); a_p = wredf(a_p);
  if (lane == 0) { s_red[wv][0] = a_c; s_red[wv][1] = a_pt; s_red[wv][2] = a_p; }
  __syncthreads();
  if (tid == 0) {
    float rc = 0, rpt = 0, rp = 0;
    for (int w = 0; w < 4; ++w) { rc += s_red[w][0]; rpt += s_red[w][1]; rp += s_red[w][2]; }
    atomicAdd(&acc[blk & 63],     (double)rc);
    atomicAdd(&acc[64 + 8*b + 0], (double)rpt);
    atomicAdd(&acc[64 + 8*b + 1], (double)rp);
  }
}

__global__ void k_final(const double* __restrict__ acc, const double* __restrict__ tpart,
                        float* __restrict__ out) {
  int t = threadIdx.x;  // 64 threads = 1 wave
  double cs = acc[t];
  double TP = acc[64 + 8*t], Ps = acc[64 + 8*t + 1];
  double Ts = 0.0;
  for (int j = 0; j < 32; ++j) Ts += tpart[t * 32 + j];
  double FP = Ps - TP, FN = Ts - TP;
  double tv = (TP + 1e-6) / (TP + 0.3 * FP + 0.7 * FN + 1e-6);
  double om = 1.0 - tv;
  if (om < 0.0) om = 0.0;
  double term = pow(om, 1.0 / 1.33);
#pragma unroll
  for (int o = 32; o > 0; o >>= 1) {
    cs   += __shfl_down(cs, o, 64);
    term += __shfl_down(term, o, 64);
  }
  if (t == 0) {
    double ftl = term / 64.0;
    double n = (double)NTOT;
    out[0] = (float)(ftl - 0.6931471805599453 * cs / n);  // bce = -ln2 * log2(q)
  }
}

extern "C" void kernel_launch(void* const* d_in, const int* in_sizes, int n_in,
                              void* d_out, int out_size, void* d_ws, size_t ws_size,
                              hipStream_t stream) {
  (void)in_sizes; (void)n_in; (void)out_size; (void)ws_size;
  const float* pred = (const float*)d_in[0];
  const float* tgt  = (const float*)d_in[1];
  unsigned char* vtb = (unsigned char*)d_ws;
  double* acc = (double*)((char*)d_ws + NTOT);
  double* tpart = acc + ACC_MAIN_DOUBLES;

  k_vsum<<<VS_BLOCKS, 256, 0, stream>>>(tgt, vtb, acc, tpart);
  k_main<<<BB * 128, 256, 0, stream>>>(pred, vtb, acc);
  k_final<<<1, 64, 0, stream>>>(acc, tpart, (float*)d_out);
}

// Round 8
// 70.095 us; speedup vs baseline: 1.1574x; 1.0865x over previous
//
#include <hip/hip_runtime.h>
#include <math.h>

#define BB 64
#define HH 512
#define WW 512
#define HWQ (HH*WW)
#define NTOT ((size_t)BB*HWQ)
#define PR 15

// ws layout:
//  [0, NTOT) bytes : vt8 per px = vsum(0..31) | t<<5 | t(y-1)<<6 | t(y+1)<<7
//  then doubles:
//   [0..63]      a_c slots (k_main atomics; zeroed by k_vsum)
//   [64+8b+0,1]  TP_b, sumP_b (k_main atomics; zeroed by k_vsum)
//   [576+swz]    k_vsum per-block t-count partials (plain stores)
#define ACC_MAIN_DOUBLES 576
#define VS_BLOCKS 1024

__device__ inline float wredf(float v) {
#pragma unroll
  for (int o = 32; o > 0; o >>= 1) v += __shfl_down(v, o, 64);
  return v;
}

// vertical 31-tap box sum + 3-row t-bit context -> one byte/px.
// float4 loads, 4 cols/thread, 16-row segments, 1024 blocks, XCD-chunked swizzle.
__global__ __launch_bounds__(256) void k_vsum(const float* __restrict__ tgt,
                                              unsigned char* __restrict__ vt,
                                              double* __restrict__ accz,
                                              double* __restrict__ tpart) {
  if (blockIdx.x == 0) {
    for (int i = threadIdx.x; i < ACC_MAIN_DOUBLES; i += 256) accz[i] = 0.0;
  }
  int blk = (int)blockIdx.x;
  int swz = (blk & 7) * (VS_BLOCKS / 8) + (blk >> 3);   // bijective XCD chunking
  int gid = swz * 256 + threadIdx.x;          // 262144 threads
  int x   = (gid & 127) * 4;                  // 128 float4 col groups
  int seg = (gid >> 7) & 31;                  // 32 segments of 16 rows
  int b   = gid >> 12;                        // 4096 threads per image
  const float* timg = tgt + (size_t)b * HWQ;
  unsigned char* vimg = vt + (size_t)b * HWQ;
  int y0 = seg * 16;
  int lo = y0 - PR; if (lo < 0) lo = 0;
  float s0 = 0.f, s1 = 0.f, s2 = 0.f, s3 = 0.f;
  unsigned r0 = 0u, r1 = 0u, r2 = 0u, r3 = 0u;   // t-bit shift regs (newest = bit0)
  for (int r = lo; r <= y0 + PR; ++r) {
    const float4 t = *(const float4*)(timg + (size_t)r * WW + x);
    s0 += t.x; s1 += t.y; s2 += t.z; s3 += t.w;
    r0 = (r0 << 1) | ((__float_as_uint(t.x) >> 29) & 1u);  // 1.0f -> 1, 0.0f -> 0
    r1 = (r1 << 1) | ((__float_as_uint(t.y) >> 29) & 1u);
    r2 = (r2 << 1) | ((__float_as_uint(t.z) >> 29) & 1u);
    r3 = (r3 << 1) | ((__float_as_uint(t.w) >> 29) & 1u);
  }
  int tcnt = 0;
#pragma unroll 4
  for (int y = y0; y < y0 + 16; ++y) {
    // bit15 = t(y), bit16 = t(y-1), bit14 = t(y+1); OOB rows shift in zeros
    unsigned b0 = (unsigned)(s0 + 0.5f) | ((r0 >> 10) & 0x20u) | (((r0 >> 16) & 1u) << 6) | (((r0 >> 14) & 1u) << 7);
    unsigned b1 = (unsigned)(s1 + 0.5f) | ((r1 >> 10) & 0x20u) | (((r1 >> 16) & 1u) << 6) | (((r1 >> 14) & 1u) << 7);
    unsigned b2 = (unsigned)(s2 + 0.5f) | ((r2 >> 10) & 0x20u) | (((r2 >> 16) & 1u) << 6) | (((r2 >> 14) & 1u) << 7);
    unsigned b3 = (unsigned)(s3 + 0.5f) | ((r3 >> 10) & 0x20u) | (((r3 >> 16) & 1u) << 6) | (((r3 >> 14) & 1u) << 7);
    *(unsigned*)(vimg + (size_t)y * WW + x) = b0 | (b1 << 8) | (b2 << 16) | (b3 << 24);
    tcnt += (int)((r0 >> 15) & 1u) + (int)((r1 >> 15) & 1u)
          + (int)((r2 >> 15) & 1u) + (int)((r3 >> 15) & 1u);
    int ra = y + PR + 1, rs = y - PR;
    if (ra < HH) {
      const float4 t = *(const float4*)(timg + (size_t)ra * WW + x);
      s0 += t.x; s1 += t.y; s2 += t.z; s3 += t.w;
      r0 = (r0 << 1) | ((__float_as_uint(t.x) >> 29) & 1u);
      r1 = (r1 << 1) | ((__float_as_uint(t.y) >> 29) & 1u);
      r2 = (r2 << 1) | ((__float_as_uint(t.z) >> 29) & 1u);
      r3 = (r3 << 1) | ((__float_as_uint(t.w) >> 29) & 1u);
    } else { r0 <<= 1; r1 <<= 1; r2 <<= 1; r3 <<= 1; }
    if (rs >= 0) {
      const float4 t = *(const float4*)(timg + (size_t)rs * WW + x);
      s0 -= t.x; s1 -= t.y; s2 -= t.z; s3 -= t.w;
    }
  }
  float tf = wredf((float)tcnt);              // exact: block sum <= 16384
  __shared__ float s_t[4];
  int wv = threadIdx.x >> 6, lane = threadIdx.x & 63;
  if (lane == 0) s_t[wv] = tf;
  __syncthreads();
  if (threadIdx.x == 0)
    tpart[swz] = (double)(s_t[0] + s_t[1] + s_t[2] + s_t[3]);
}

// 8-byte-granular masked load (col boundaries are 8B-aligned)
__device__ inline uint2 ld8(const unsigned char* __restrict__ row, int off) {
  bool ok = (off >= 0) & (off <= WW - 8);
  int oc = ok ? off : 0;
  uint2 v = *(const uint2*)(row + oc);
  if (!ok) { v.x = 0u; v.y = 0u; }
  return v;
}

__device__ inline int sum4b(unsigned x) {     // sum of the 4 bytes
  unsigned t = (x & 0x00FF00FFu) + ((x >> 8) & 0x00FF00FFu);
  return (int)((t + (t >> 16)) & 0xFFFFu);
}

// window byte I (0..39) <-> col x0-16+I ; I compile-time -> folds to one bfe
#define VTW(I) ((I) < 8  ? (((I)&7) < 4 ? w0.x : w0.y) : \
                (I) < 16 ? (((I)&7) < 4 ? w1.x : w1.y) : \
                (I) < 24 ? (((I)&7) < 4 ? w2.x : w2.y) : \
                (I) < 32 ? (((I)&7) < 4 ? w3.x : w3.y) : \
                           (((I)&7) < 4 ? w4.x : w4.y))
#define BGET5(I) ((int)((VTW(I) >> (((I)&3)*8)) & 31u))   // 5-bit vsum field

#define UB(W,J) ((int)(((W) >> (8*(J))) & 7u))            // u byte (0..4)
#define VB(W,J) ((int)(((W) >> (8*(J))) & 3u))            // v+1 byte (0..2)

// one output column
#define STEP(C, UM, UP, VM, VC, VP, TCI, PV) do {                     \
    int gx = (UP) - (UM);                                             \
    int gy = (VM) + 2*(VC) + (VP) - 4;                                \
    float tb = __builtin_amdgcn_sqrtf((float)(gx*gx + gy*gy) + 1e-12f); \
    float qq = (TCI) ? (PV) : 1.f - (PV);                             \
    float lg = __log2f(qq);                                           \
    int   di = (TCI) ? (961 - sw) : sw;                               \
    float wgt = fmaf(5.f, tb, fmaf(1.5608741e-3f, (float)di, 0.8f));  \
    a_c = fmaf(wgt, lg, a_c);                                         \
    a_pt += (TCI) ? (PV) : 0.f;                                       \
    a_p  += (PV);                                                     \
    sw += BGET5((C)+32) - BGET5((C)+1);                               \
  } while (0)

// main fused kernel: reads ONLY pred f32 + one vt8 row window per output row.
__global__ __launch_bounds__(256) void k_main(const float* __restrict__ pred,
                                              const unsigned char* __restrict__ vt,
                                              double* __restrict__ acc) {
  __shared__ float s_red[4][3];
  int blk = blockIdx.x;            // BB*128
  int b   = blk >> 7;
  int y0  = (blk & 127) * 4;
  int tid = threadIdx.x;
  int wv = tid >> 6, lane = tid & 63;
  int y  = y0 + wv;
  int x0 = lane * 8;

  const float* prow = pred + (size_t)b * HWQ + (size_t)y * WW + x0;
  float4 pA = *(const float4*)prow;
  float4 pB = *(const float4*)(prow + 4);

  const unsigned char* vrow = vt + (size_t)b * HWQ + (size_t)y * WW;
  uint2 w0 = ld8(vrow, x0 - 16);
  uint2 w1 = ld8(vrow, x0 - 8);
  uint2 w2 = *(const uint2*)(vrow + x0);      // always in-bounds
  uint2 w3 = ld8(vrow, x0 + 8);
  uint2 w4 = ld8(vrow, x0 + 16);

  // packed-byte vertical sobel composites from embedded m/z/q bits
  unsigned zl = (w2.x >> 5) & 0x01010101u, zh = (w2.y >> 5) & 0x01010101u;
  unsigned ml = (w2.x >> 6) & 0x01010101u, mh = (w2.y >> 6) & 0x01010101u;
  unsigned ql = (w2.x >> 7) & 0x01010101u, qh = (w2.y >> 7) & 0x01010101u;
  unsigned uLo = ml + ql + 2u * zl;           // u = m+2z+q, bytes 0..4
  unsigned uHi = mh + qh + 2u * zh;
  unsigned vLo = (ql + 0x01010101u) - ml;     // v+1, bytes 0..2 (no borrow)
  unsigned vHi = (qh + 0x01010101u) - mh;
  // halos: col x0-1 = byte7 of w1 (0-masked at edge), col x0+8 = byte0 of w3
  int zm1 = (int)((w1.y >> 29) & 1u), mm1 = (int)((w1.y >> 30) & 1u), qm1 = (int)(w1.y >> 31);
  int zp8 = (int)((w3.x >> 5) & 1u),  mp8 = (int)((w3.x >> 6) & 1u),  qp8 = (int)((w3.x >> 7) & 1u);
  int uM1 = mm1 + 2*zm1 + qm1, vM1 = qm1 - mm1 + 1;
  int uP8 = mp8 + 2*zp8 + qp8, vP8 = qp8 - mp8 + 1;

  int u0=UB(uLo,0), u1=UB(uLo,1), u2c=UB(uLo,2), u3=UB(uLo,3);
  int u4=UB(uHi,0), u5=UB(uHi,1), u6=UB(uHi,2), u7=UB(uHi,3);
  int v0=VB(vLo,0), v1=VB(vLo,1), v2c=VB(vLo,2), v3=VB(vLo,3);
  int v4=VB(vHi,0), v5=VB(vHi,1), v6=VB(vHi,2), v7=VB(vHi,3);
  int t0=(int)((w2.x>>5)&1u),  t1=(int)((w2.x>>13)&1u), t2=(int)((w2.x>>21)&1u), t3=(int)((w2.x>>29)&1u);
  int t4=(int)((w2.y>>5)&1u),  t5=(int)((w2.y>>13)&1u), t6=(int)((w2.y>>21)&1u), t7=(int)((w2.y>>29)&1u);

  // initial 31-window vsum for col x0: bytes 1..31 (5-bit fields, packed adds, max 248)
  unsigned p0 = (w0.x & 0x1F1F1F1Fu) + (w0.y & 0x1F1F1F1Fu)
              + (w1.x & 0x1F1F1F1Fu) + (w1.y & 0x1F1F1F1Fu)
              + (w2.x & 0x1F1F1F1Fu) + (w2.y & 0x1F1F1F1Fu)
              + (w3.x & 0x1F1F1F1Fu) + (w3.y & 0x1F1F1F1Fu);
  int sw = sum4b(p0) - (int)(w0.x & 0x1Fu);

  float a_c = 0.f, a_pt = 0.f, a_p = 0.f;
  STEP(0, uM1, u1,  vM1, v0,  v1,  t0, pA.x);
  STEP(1, u0,  u2c, v0,  v1,  v2c, t1, pA.y);
  STEP(2, u1,  u3,  v1,  v2c, v3,  t2, pA.z);
  STEP(3, u2c, u4,  v2c, v3,  v4,  t3, pA.w);
  STEP(4, u3,  u5,  v3,  v4,  v5,  t4, pB.x);
  STEP(5, u4,  u6,  v4,  v5,  v6,  t5, pB.y);
  STEP(6, u5,  u7,  v5,  v6,  v7,  t6, pB.z);
  STEP(7, u6,  uP8, v6,  v7,  vP8, t7, pB.w);

  a_c = wredf(a_c); a_pt = wredf(a_pt); a_p = wredf(a_p);
  if (lane == 0) { s_red[wv][0] = a_c; s_red[wv][1] = a_pt; s_red[wv][2] = a_p; }
  __syncthreads();
  if (tid == 0) {
    float rc = 0, rpt = 0, rp = 0;
    for (int w = 0; w < 4; ++w) { rc += s_red[w][0]; rpt += s_red[w][1]; rp += s_red[w][2]; }
    atomicAdd(&acc[blk & 63],     (double)rc);
    atomicAdd(&acc[64 + 8*b + 0], (double)rpt);
    atomicAdd(&acc[64 + 8*b + 1], (double)rp);
  }
}

__global__ void k_final(const double* __restrict__ acc, const double* __restrict__ tpart,
                        float* __restrict__ out) {
  int t = threadIdx.x;  // 64 threads = 1 wave; t = image index
  double cs = acc[t];
  double TP = acc[64 + 8*t], Ps = acc[64 + 8*t + 1];
  double Ts = 0.0;
  for (int j = 0; j < 16; ++j) Ts += tpart[t * 16 + j];   // tpart indexed by swz: 16/image
  double FP = Ps - TP, FN = Ts - TP;
  double tv = (TP + 1e-6) / (TP + 0.3 * FP + 0.7 * FN + 1e-6);
  double om = 1.0 - tv;
  if (om < 0.0) om = 0.0;
  double term = pow(om, 1.0 / 1.33);
#pragma unroll
  for (int o = 32; o > 0; o >>= 1) {
    cs   += __shfl_down(cs, o, 64);
    term += __shfl_down(term, o, 64);
  }
  if (t == 0) {
    double ftl = term / 64.0;
    double n = (double)NTOT;
    out[0] = (float)(ftl - 0.6931471805599453 * cs / n);  // bce = -ln2 * log2(q)
  }
}

extern "C" void kernel_launch(void* const* d_in, const int* in_sizes, int n_in,
                              void* d_out, int out_size, void* d_ws, size_t ws_size,
                              hipStream_t stream) {
  (void)in_sizes; (void)n_in; (void)out_size; (void)ws_size;
  const float* pred = (const float*)d_in[0];
  const float* tgt  = (const float*)d_in[1];
  unsigned char* vtb = (unsigned char*)d_ws;
  double* acc = (double*)((char*)d_ws + NTOT);
  double* tpart = acc + ACC_MAIN_DOUBLES;

  k_vsum<<<VS_BLOCKS, 256, 0, stream>>>(tgt, vtb, acc, tpart);
  k_main<<<BB * 128, 256, 0, stream>>>(pred, vtb, acc);
  k_final<<<1, 64, 0, stream>>>(acc, tpart, (float*)d_out);
}

// Round 10
// 64.246 us; speedup vs baseline: 1.2628x; 1.0910x over previous
//
#include <hip/hip_runtime.h>
#include <math.h>

#define BB 64
#define HH 512
#define WW 512
#define HWQ (HH*WW)
#define NTOT ((size_t)BB*HWQ)

// ws layout:
//  [0, 2MB)  : target bitmask, 1 bit/px (word w covers px 32w..32w+31)
//  then doubles:
//   [0..63]      a_c slots (k_main atomics; zeroed by k_bits block 0)
//   [64+8b+0,1]  TP_b, sumP_b (k_main atomics; zeroed by k_bits block 0)
//   [576+blk]    k_bits per-block t-count partials (plain stores)
#define BITS_BYTES (NTOT / 8)
#define ACC_MAIN_DOUBLES 576

// target f32 -> bitmask + per-block t-count. 2048 blocks, 32 px/thread.
__global__ __launch_bounds__(256) void k_bits(const float* __restrict__ tgt,
                                              unsigned* __restrict__ bits,
                                              double* __restrict__ accz,
                                              double* __restrict__ tpart) {
  if (blockIdx.x == 0) {
    for (int i = threadIdx.x; i < ACC_MAIN_DOUBLES; i += 256) accz[i] = 0.0;
  }
  size_t base = (size_t)blockIdx.x * 8192 + (size_t)threadIdx.x * 32;
  const float* p = tgt + base;
  unsigned wrd = 0u;
#pragma unroll
  for (int k = 0; k < 8; ++k) {
    const float4 t = *(const float4*)(p + 4 * k);
    wrd |= ((__float_as_uint(t.x) >> 29) & 1u) << (4 * k + 0);   // 1.0f -> 1, 0.0f -> 0
    wrd |= ((__float_as_uint(t.y) >> 29) & 1u) << (4 * k + 1);
    wrd |= ((__float_as_uint(t.z) >> 29) & 1u) << (4 * k + 2);
    wrd |= ((__float_as_uint(t.w) >> 29) & 1u) << (4 * k + 3);
  }
  bits[(size_t)blockIdx.x * 256 + threadIdx.x] = wrd;
  int cnt = __popc(wrd);
#pragma unroll
  for (int o = 32; o > 0; o >>= 1) cnt += __shfl_down(cnt, o, 64);
  __shared__ int s_t[4];
  int wv = threadIdx.x >> 6, lane = threadIdx.x & 63;
  if (lane == 0) s_t[wv] = cnt;
  __syncthreads();
  if (threadIdx.x == 0)
    tpart[blockIdx.x] = (double)(s_t[0] + s_t[1] + s_t[2] + s_t[3]);
}

__device__ inline float wredf(float v) {
#pragma unroll
  for (int o = 32; o > 0; o >>= 1) v += __shfl_down(v, o, 64);
  return v;
}

__device__ inline int sum4b(unsigned x) {     // sum of the 4 bytes
  unsigned t = (x & 0x00FF00FFu) + ((x >> 8) & 0x00FF00FFu);
  return (int)((t + (t >> 16)) & 0xFFFFu);
}

// window byte I (0..39) <-> col x0-16+I ; I compile-time -> folds to one bfe
#define VTW(I) ((I) < 8  ? (((I)&7) < 4 ? w0.x : w0.y) : \
                (I) < 16 ? (((I)&7) < 4 ? w1.x : w1.y) : \
                (I) < 24 ? (((I)&7) < 4 ? w2.x : w2.y) : \
                (I) < 32 ? (((I)&7) < 4 ? w3.x : w3.y) : \
                           (((I)&7) < 4 ? w4.x : w4.y))
#define BGET5(I) ((int)((VTW(I) >> (((I)&3)*8)) & 31u))   // vsum byte (<=31)

// one output column (identical math to R8, which passed)
#define STEP(C, UM, UP, VM, VC, VP, TCI, PV) do {                     \
    int gx = (UP) - (UM);                                             \
    int gy = (VM) + 2*(VC) + (VP) - 4;                                \
    float tb = __builtin_amdgcn_sqrtf((float)(gx*gx + gy*gy) + 1e-12f); \
    float qq = (TCI) ? (PV) : 1.f - (PV);                             \
    float lg = __log2f(qq);                                           \
    int   di = (TCI) ? (961 - sw) : sw;                               \
    float wgt = fmaf(5.f, tb, fmaf(1.5608741e-3f, (float)di, 0.8f));  \
    a_c = fmaf(wgt, lg, a_c);                                         \
    a_pt += (TCI) ? (PV) : 0.f;                                       \
    a_p  += (PV);                                                     \
    sw += BGET5((C)+32) - BGET5((C)+1);                               \
  } while (0)

// SWAR spread-add of one staged bit-row word into an acc class
#define SPREAD_ADD(RR, CC) do {                                          \
    unsigned bw_ = l_bits[(RR) * 20 + 2 + w];                            \
    unsigned* ac_ = &l_acc[(CC) * 128 + w * 8];                          \
    atomicAdd(&ac_[0], (((bw_ >>  0) & 0xFu) * 0x00204081u) & 0x01010101u); \
    atomicAdd(&ac_[1], (((bw_ >>  4) & 0xFu) * 0x00204081u) & 0x01010101u); \
    atomicAdd(&ac_[2], (((bw_ >>  8) & 0xFu) * 0x00204081u) & 0x01010101u); \
    atomicAdd(&ac_[3], (((bw_ >> 12) & 0xFu) * 0x00204081u) & 0x01010101u); \
    atomicAdd(&ac_[4], (((bw_ >> 16) & 0xFu) * 0x00204081u) & 0x01010101u); \
    atomicAdd(&ac_[5], (((bw_ >> 20) & 0xFu) * 0x00204081u) & 0x01010101u); \
    atomicAdd(&ac_[6], (((bw_ >> 24) & 0xFu) * 0x00204081u) & 0x01010101u); \
    atomicAdd(&ac_[7], (((bw_ >> 28) & 0xFu) * 0x00204081u) & 0x01010101u); \
  } while (0)

// main fused kernel: block = 4 rows of one image; everything target-derived
// comes from 34 staged bit-rows (2.2 KB) + cooperative SWAR vertical sums.
__global__ __launch_bounds__(256) void k_main(const float* __restrict__ pred,
                                              const unsigned* __restrict__ bits,
                                              double* __restrict__ acc) {
  __shared__ unsigned l_bits[34 * 20];   // per row: [8B pad | 64B bits | 8B pad]
  __shared__ unsigned l_acc[7 * 128];    // 0=common(k3..30), 1..3=rows k0,1,2, 4..6=rows k31,32,33
  __shared__ unsigned l_vs[4 * 136];     // per emitted row: [16B pad | 512 vsum bytes | 16B pad]
  __shared__ float s_red[4][3];

  int blk = blockIdx.x;                  // BB*128
  int b   = blk >> 7;
  int y0  = (blk & 127) * 4;
  int tid = threadIdx.x;
  int wv  = tid >> 6, lane = tid & 63;
  int y   = y0 + wv;
  int x0  = lane * 8;

  // pred loads hoisted above all staging (hide global latency)
  const float* prow = pred + (size_t)b * HWQ + (size_t)y * WW + x0;
  float4 pA = *(const float4*)prow;
  float4 pB = *(const float4*)(prow + 4);

  // zero SWAR accumulators
  for (int i = tid; i < 7 * 128; i += 256) l_acc[i] = 0u;
  // stage bit rows y0-15 .. y0+18 (k=0..33), 16B quarters, OOB rows = 0
  const uint4* bimg4 = (const uint4*)(bits + (size_t)b * (HWQ / 32));
  for (int i = tid; i < 34 * 4; i += 256) {
    int r = i >> 2, q = i & 3;
    int gy = y0 - 15 + r;
    uint4 v = make_uint4(0u, 0u, 0u, 0u);
    if (gy >= 0 && gy < HH) v = bimg4[gy * 4 + q];
    unsigned* dst = &l_bits[r * 20 + 2 + q * 4];
    dst[0] = v.x; dst[1] = v.y; dst[2] = v.z; dst[3] = v.w;
  }
  if (tid < 34 * 4) {                    // zero the 4 pad words per row
    int r = tid >> 2, pw = tid & 3;
    l_bits[r * 20 + (pw < 2 ? pw : 16 + pw)] = 0u;
  }
  __syncthreads();

  // cooperative vertical sums: thread (w,g) handles word w of rows {g, g+16, g+32}
  {
    int w = tid & 15, g = tid >> 4;
    int r1 = g;       int c1 = (r1 < 3) ? 1 + r1 : 0;
    SPREAD_ADD(r1, c1);
    int r2 = g + 16;  int c2 = (r2 > 30) ? 4 + (r2 - 31) : 0;
    SPREAD_ADD(r2, c2);
    if (g < 2) { int r3 = g + 32; SPREAD_ADD(r3, 4 + (r3 - 31)); }
  }
  __syncthreads();

  // combine: vsum(i) = common + e_i + e_{i+1} + e_{i+2}  (e0..e2=rows 0..2, e3..e5=rows 31..33)
  for (int task = tid; task < 544; task += 256) {
    if (task < 512) {
      int i = task >> 7, j = task & 127;
      l_vs[i * 136 + 4 + j] = l_acc[j] + l_acc[(1 + i) * 128 + j]
                            + l_acc[(2 + i) * 128 + j] + l_acc[(3 + i) * 128 + j];
    } else {
      int t2 = task - 512;               // 32 pad-word tasks
      int i = t2 >> 3, pw = t2 & 7;
      l_vs[i * 136 + (pw < 4 ? pw : 128 + pw)] = 0u;
    }
  }
  __syncthreads();

  // per-lane vsum byte windows (cols x0-16 .. x0+23), 8B-aligned LDS reads
  const char* vsrow = (const char*)&l_vs[wv * 136];
  uint2 w0 = *(const uint2*)(vsrow + 8 * lane);
  uint2 w1 = *(const uint2*)(vsrow + 8 * lane + 8);
  uint2 w2 = *(const uint2*)(vsrow + 8 * lane + 16);
  uint2 w3 = *(const uint2*)(vsrow + 8 * lane + 24);
  uint2 w4 = *(const uint2*)(vsrow + 8 * lane + 32);

  // sobel 10-bit windows (cols x0-1 .. x0+8) for rows y-1, y, y+1 (k = wv+14..wv+16)
  int wb = (lane + 7) >> 2;
  int sh = ((lane + 7) & 3) * 8 + 7;
  const unsigned* rm = &l_bits[(wv + 14) * 20];
  const unsigned* rz = &l_bits[(wv + 15) * 20];
  const unsigned* rq = &l_bits[(wv + 16) * 20];
  unsigned wm = (unsigned)((((((unsigned long long)rm[wb + 1]) << 32) | rm[wb]) >> sh) & 0x3FFull);
  unsigned wz = (unsigned)((((((unsigned long long)rz[wb + 1]) << 32) | rz[wb]) >> sh) & 0x3FFull);
  unsigned wq = (unsigned)((((((unsigned long long)rq[wb + 1]) << 32) | rq[wb]) >> sh) & 0x3FFull);

  // u = m+2z+q (0..4), vv = q-m+1 (0..2) per window col j (0..9)
  int u0 = (int)((wm>>0)&1u) + 2*(int)((wz>>0)&1u) + (int)((wq>>0)&1u);
  int u1 = (int)((wm>>1)&1u) + 2*(int)((wz>>1)&1u) + (int)((wq>>1)&1u);
  int u2 = (int)((wm>>2)&1u) + 2*(int)((wz>>2)&1u) + (int)((wq>>2)&1u);
  int u3 = (int)((wm>>3)&1u) + 2*(int)((wz>>3)&1u) + (int)((wq>>3)&1u);
  int u4 = (int)((wm>>4)&1u) + 2*(int)((wz>>4)&1u) + (int)((wq>>4)&1u);
  int u5 = (int)((wm>>5)&1u) + 2*(int)((wz>>5)&1u) + (int)((wq>>5)&1u);
  int u6 = (int)((wm>>6)&1u) + 2*(int)((wz>>6)&1u) + (int)((wq>>6)&1u);
  int u7 = (int)((wm>>7)&1u) + 2*(int)((wz>>7)&1u) + (int)((wq>>7)&1u);
  int u8 = (int)((wm>>8)&1u) + 2*(int)((wz>>8)&1u) + (int)((wq>>8)&1u);
  int u9 = (int)((wm>>9)&1u) + 2*(int)((wz>>9)&1u) + (int)((wq>>9)&1u);
  int vv0 = (int)((wq>>0)&1u) - (int)((wm>>0)&1u) + 1;
  int vv1 = (int)((wq>>1)&1u) - (int)((wm>>1)&1u) + 1;
  int vv2 = (int)((wq>>2)&1u) - (int)((wm>>2)&1u) + 1;
  int vv3 = (int)((wq>>3)&1u) - (int)((wm>>3)&1u) + 1;
  int vv4 = (int)((wq>>4)&1u) - (int)((wm>>4)&1u) + 1;
  int vv5 = (int)((wq>>5)&1u) - (int)((wm>>5)&1u) + 1;
  int vv6 = (int)((wq>>6)&1u) - (int)((wm>>6)&1u) + 1;
  int vv7 = (int)((wq>>7)&1u) - (int)((wm>>7)&1u) + 1;
  int vv8 = (int)((wq>>8)&1u) - (int)((wm>>8)&1u) + 1;
  int vv9 = (int)((wq>>9)&1u) - (int)((wm>>9)&1u) + 1;
  int t0 = (int)((wz>>1)&1u), t1 = (int)((wz>>2)&1u), t2 = (int)((wz>>3)&1u), t3 = (int)((wz>>4)&1u);
  int t4 = (int)((wz>>5)&1u), t5 = (int)((wz>>6)&1u), t6 = (int)((wz>>7)&1u), t7 = (int)((wz>>8)&1u);

  // initial 31-window sum for col x0: bytes 1..31 of the 40-byte window
  unsigned p0s = w0.x + w0.y + w1.x + w1.y + w2.x + w2.y + w3.x + w3.y;  // byte sums <= 248
  int sw = sum4b(p0s) - (int)(w0.x & 0xFFu);

  float a_c = 0.f, a_pt = 0.f, a_p = 0.f;
  STEP(0, u0, u2, vv0, vv1, vv2, t0, pA.x);
  STEP(1, u1, u3, vv1, vv2, vv3, t1, pA.y);
  STEP(2, u2, u4, vv2, vv3, vv4, t2, pA.z);
  STEP(3, u3, u5, vv3, vv4, vv5, t3, pA.w);
  STEP(4, u4, u6, vv4, vv5, vv6, t4, pB.x);
  STEP(5, u5, u7, vv5, vv6, vv7, t5, pB.y);
  STEP(6, u6, u8, vv6, vv7, vv8, t6, pB.z);
  STEP(7, u7, u9, vv7, vv8, vv9, t7, pB.w);

  a_c = wredf(a_c); a_pt = wredf(a_pt); a_p = wredf(a_p);
  if (lane == 0) { s_red[wv][0] = a_c; s_red[wv][1] = a_pt; s_red[wv][2] = a_p; }
  __syncthreads();
  if (tid == 0) {
    float rc = 0, rpt = 0, rp = 0;
    for (int w = 0; w < 4; ++w) { rc += s_red[w][0]; rpt += s_red[w][1]; rp += s_red[w][2]; }
    atomicAdd(&acc[blk & 63],     (double)rc);
    atomicAdd(&acc[64 + 8*b + 0], (double)rpt);
    atomicAdd(&acc[64 + 8*b + 1], (double)rp);
  }
}

__global__ void k_final(const double* __restrict__ acc, const double* __restrict__ tpart,
                        float* __restrict__ out) {
  int t = threadIdx.x;  // 64 threads = 1 wave; t = image index
  double cs = acc[t];
  double TP = acc[64 + 8*t], Ps = acc[64 + 8*t + 1];
  double Ts = 0.0;
  for (int j = 0; j < 32; ++j) Ts += tpart[t * 32 + j];   // 32 k_bits blocks per image
  double FP = Ps - TP, FN = Ts - TP;
  double tv = (TP + 1e-6) / (TP + 0.3 * FP + 0.7 * FN + 1e-6);
  double om = 1.0 - tv;
  if (om < 0.0) om = 0.0;
  double term = pow(om, 1.0 / 1.33);
#pragma unroll
  for (int o = 32; o > 0; o >>= 1) {
    cs   += __shfl_down(cs, o, 64);
    term += __shfl_down(term, o, 64);
  }
  if (t == 0) {
    double ftl = term / 64.0;
    double n = (double)NTOT;
    out[0] = (float)(ftl - 0.6931471805599453 * cs / n);  // bce = -ln2 * log2(q)
  }
}

extern "C" void kernel_launch(void* const* d_in, const int* in_sizes, int n_in,
                              void* d_out, int out_size, void* d_ws, size_t ws_size,
                              hipStream_t stream) {
  (void)in_sizes; (void)n_in; (void)out_size; (void)ws_size;
  const float* pred = (const float*)d_in[0];
  const float* tgt  = (const float*)d_in[1];
  unsigned* bits = (unsigned*)d_ws;
  double* acc = (double*)((char*)d_ws + BITS_BYTES);
  double* tpart = acc + ACC_MAIN_DOUBLES;

  k_bits<<<(int)(NTOT / 8192), 256, 0, stream>>>(tgt, bits, acc, tpart);
  k_main<<<BB * 128, 256, 0, stream>>>(pred, bits, acc);
  k_final<<<1, 64, 0, stream>>>(acc, tpart, (float*)d_out);
}